// Round 1
// 225.223 us; speedup vs baseline: 1.0300x; 1.0300x over previous
//
#include <hip/hip_runtime.h>
#include <hip/hip_bf16.h>
#include <stdint.h>

// Problem constants (fixed by the reference)
#define NS   8192
#define XD   512
#define HD   2048
#define YD   512

typedef unsigned short u16;
using bf16x8 = __attribute__((ext_vector_type(8))) short;
using f32x4  = __attribute__((ext_vector_type(4))) float;

__device__ __forceinline__ float bf2f(u16 u) {
  union { uint32_t i; float f; } v; v.i = ((uint32_t)u) << 16; return v.f;
}
__device__ __forceinline__ u16 f2b(float f) {
  __hip_bfloat16 hb = __float2bfloat16(f);
  return *(const u16*)&hb;
}
// dtype-adaptive element load: f32 flag ? read float : read bf16
__device__ __forceinline__ float ld_in(const void* p, int f32, size_t i) {
  return f32 ? ((const float*)p)[i] : bf2f(((const u16*)p)[i]);
}
#define GLDS(gp, lp) __builtin_amdgcn_global_load_lds( \
    (__attribute__((address_space(1))) void*)(gp),     \
    (__attribute__((address_space(3))) void*)(lp), 16, 0, 0)

// ---------------- per-block dtype self-detection ----------------------------
__device__ __forceinline__ int probe_f32(const void* p, int n_u16, int* sflag) {
  if (threadIdx.x == 0) *sflag = 0;
  __syncthreads();
  const u16* q = (const u16*)p;
  int wild = 0;
  for (int i = threadIdx.x; i < n_u16; i += blockDim.x) {
    float v = bf2f(q[i]);
    if (!(fabsf(v) <= 1000.0f)) wild = 1;   // catches huge AND NaN
  }
  if (wild) *sflag = 1;
  __syncthreads();
  int r = *sflag;
  __syncthreads();                          // safe for back-to-back reuse
  return r;
}

// ---------------- fused prep: x->bf16, biases, 4 transposes, ystats ---------
// grid: [0,2048) x-convert | 2048 biases | [2049,3073) transposes |
//       [3073,3137) y column stats (moved out of gemm1; only gemm2 needs them)
__global__ __launch_bounds__(256) void prep_all(
    const void* __restrict__ x,
    const void* w1m, const void* b1m, const void* w2m, const void* b2m,
    const void* w1l, const void* b1l, const void* w2l, const void* b2l,
    const void* __restrict__ y,
    u16* __restrict__ xb, float* __restrict__ biasv,
    u16* __restrict__ W1t, u16* __restrict__ W2tm, u16* __restrict__ W2tl,
    float* __restrict__ Sy, float* __restrict__ Sy2) {
  __shared__ u16 tile[64 * 72];              // transpose staging (9216 B)
  __shared__ int sflag;
  const int b = blockIdx.x;
  const int tid = threadIdx.x;

  if (b < 2048) {                            // ---- x conversion (f32 only)
    if (!probe_f32(x, 1024, &sflag)) return; // bf16 -> gemm1 reads x directly
    const size_t base = (size_t)b * 2048 + (size_t)tid * 8;
    alignas(16) u16 o[8];
    const float4* s = (const float4*)((const float*)x + base);
    float4 v0 = s[0], v1 = s[1];
    o[0]=f2b(v0.x); o[1]=f2b(v0.y); o[2]=f2b(v0.z); o[3]=f2b(v0.w);
    o[4]=f2b(v1.x); o[5]=f2b(v1.y); o[6]=f2b(v1.z); o[7]=f2b(v1.w);
    *(uint4*)(xb + base) = *(const uint4*)o;
  } else if (b == 2048) {                    // ---- biases -> f32
    const int f3 = probe_f32(b1m, 1024, &sflag);
    const int f5 = probe_f32(b2m, 512, &sflag);
    const int f7 = probe_f32(b1l, 1024, &sflag);
    const int f9 = probe_f32(b2l, 512, &sflag);
    for (int i = tid; i < 5120; i += 256) {
      float v;
      if (i < 2048)      v = ld_in(b1m, f3, i);
      else if (i < 4096) v = ld_in(b1l, f7, i - 2048);
      else if (i < 4608) v = ld_in(b2m, f5, i - 4096);
      else               v = ld_in(b2l, f9, i - 4608);
      biasv[i] = v;
    }
  } else if (b < 3073) {                     // ---- 64x64-tile transposes
    const int id = b - 2049, which = id >> 8, t = id & 255;
    const void* in; u16* out; int R, C;
    if (which == 0)      { in = w1m; out = W1t;                   R = XD; C = HD; }
    else if (which == 1) { in = w2m; out = W2tm;                  R = HD; C = YD; }
    else if (which == 2) { in = w1l; out = W1t + (size_t)HD * XD; R = XD; C = HD; }
    else                 { in = w2l; out = W2tl;                  R = HD; C = YD; }
    const int f = probe_f32(in, 1024, &sflag);
    const int nbx = C >> 6;
    const int c0 = (t % nbx) * 64, r0 = (t / nbx) * 64;
    const int r = tid >> 2, cc = (tid & 3) * 16;
    if (f) {
      const float4* s = (const float4*)((const float*)in + (size_t)(r0 + r) * C + c0 + cc);
#pragma unroll
      for (int k = 0; k < 4; ++k) {
        float4 v = s[k];
        tile[r * 72 + cc + k * 4 + 0] = f2b(v.x);
        tile[r * 72 + cc + k * 4 + 1] = f2b(v.y);
        tile[r * 72 + cc + k * 4 + 2] = f2b(v.z);
        tile[r * 72 + cc + k * 4 + 3] = f2b(v.w);
      }
    } else {
      const uint4* s = (const uint4*)((const u16*)in + (size_t)(r0 + r) * C + c0 + cc);
      *(uint4*)&tile[r * 72 + cc]     = s[0];
      *(uint4*)&tile[r * 72 + cc + 8] = s[1];
    }
    __syncthreads();
    const int i = tid >> 2, jc = (tid & 3) * 16;
    alignas(16) u16 o[16];
#pragma unroll
    for (int j = 0; j < 16; ++j) o[j] = tile[(jc + j) * 72 + i];
    uint4* dq = (uint4*)&out[(size_t)(c0 + i) * R + r0 + jc];
    dq[0] = ((const uint4*)o)[0];
    dq[1] = ((const uint4*)o)[1];
  } else {                                   // ---- y column stats (64 blocks)
    const int id2 = b - 3073;
    const int yf = probe_f32(y, 1024, &sflag);
    const int half = tid >> 7;               // 0/1
    const int c0 = (tid & 127) * 4;
    const int r0 = id2 * 128 + half * 64;
    float s0 = 0.f, s1 = 0.f, s2 = 0.f, s3 = 0.f;
    float q0 = 0.f, q1 = 0.f, q2 = 0.f, q3 = 0.f;
    for (int r = r0; r < r0 + 64; r += 4) {
#pragma unroll
      for (int rr = 0; rr < 4; ++rr) {
        float v0, v1, v2, v3;
        if (yf) {
          const float4 t4 = *(const float4*)((const float*)y + (size_t)(r + rr) * YD + c0);
          v0 = t4.x; v1 = t4.y; v2 = t4.z; v3 = t4.w;
        } else {
          const uint2 t2 = *(const uint2*)((const u16*)y + (size_t)(r + rr) * YD + c0);
          v0 = bf2f((u16)(t2.x & 0xffff)); v1 = bf2f((u16)(t2.x >> 16));
          v2 = bf2f((u16)(t2.y & 0xffff)); v3 = bf2f((u16)(t2.y >> 16));
        }
        s0 += v0; q0 += v0 * v0;  s1 += v1; q1 += v1 * v1;
        s2 += v2; q2 += v2 * v2;  s3 += v3; q3 += v3 * v3;
      }
    }
    atomicAdd(&Sy[c0],     s0);  atomicAdd(&Sy2[c0],     q0);
    atomicAdd(&Sy[c0 + 1], s1);  atomicAdd(&Sy2[c0 + 1], q1);
    atomicAdd(&Sy[c0 + 2], s2);  atomicAdd(&Sy2[c0 + 2], q2);
    atomicAdd(&Sy[c0 + 3], s3);  atomicAdd(&Sy2[c0 + 3], q3);
  }
}

// ---------------- GEMM1: 256x256 tile, 8-phase counted-vmcnt pipeline -------
// h_{mu,lv} = relu(x @ [W1m|W1l] + b1).  M=8192, N=4096, K=512.
// 512 thr = 8 waves (2M x 4N), per-wave 128x64 out.  BK=64, NKT=8, 4 iters.
// LDS 128 KB: A[buf][half][128][64] @0, B[buf][half][128][64] @32768 (u16).
// Stage-slot map (half-tile per phase; region overwrite always >=1 phase
// after its last ds_read; reads of buf computed ph1-4: B last@ph2, A last@ph3;
// buf computed ph5-8: B last@ph6, A last@ph7):
//   ph1: kt(2i+1).A0   ph2: kt(2i+1).A1   ph3: kt(2i+2).B0   ph4: kt(2i+2).B1
//   ph5: kt(2i+2).A0   ph6: kt(2i+2).A1   ph7: kt(2i+3).B0   ph8: kt(2i+3).B1
// vmcnt(4) at ph4 (waits kt(2i+1) complete; ph3+ph4's 4 loads stay in flight)
// and ph8 (waits kt(2i+2)); never vmcnt(0) in steady state.  Same XOR swizzle
// as the verified 128^2 kernel (bank conflicts were 0).  Epilogue staged
// through LDS (chunk-XOR) -> uint4 stores instead of 64 scalar u16 stores.
#define SYNC_PRE do { \
  __builtin_amdgcn_sched_barrier(0); \
  __builtin_amdgcn_s_barrier(); \
  asm volatile("s_waitcnt lgkmcnt(0)" ::: "memory"); \
  __builtin_amdgcn_sched_barrier(0); \
  __builtin_amdgcn_s_setprio(1); } while (0)
#define SYNC_POST do { \
  __builtin_amdgcn_s_setprio(0); \
  __builtin_amdgcn_sched_barrier(0); \
  __builtin_amdgcn_s_barrier(); \
  __builtin_amdgcn_sched_barrier(0); } while (0)
#define VMCNT4 asm volatile("s_waitcnt vmcnt(4)" ::: "memory")
#define VMCNT0 asm volatile("s_waitcnt vmcnt(0)" ::: "memory")

#define RD_A(MH, BUF) do { \
  const u16* ab_ = &lds[((BUF)*2 + wm) * 8192]; \
  _Pragma("unroll") for (int q_ = 0; q_ < 4; ++q_) \
    _Pragma("unroll") for (int ks_ = 0; ks_ < 2; ++ks_) \
      af[q_][ks_] = *(const bf16x8*)&ab_[((MH)*64 + q_*16 + c16)*64 + (((ks_*4+quad) ^ cswz) << 3)]; \
} while (0)

#define RD_B(NH, BUF) do { \
  const u16* bb_ = &lds[32768 + ((BUF)*2 + (wn>>1)) * 8192]; \
  _Pragma("unroll") for (int p_ = 0; p_ < 2; ++p_) \
    _Pragma("unroll") for (int ks_ = 0; ks_ < 2; ++ks_) \
      bf[(NH)*2+p_][ks_] = *(const bf16x8*)&bb_[((wn&1)*64 + ((NH)*2+p_)*16 + c16)*64 + (((ks_*4+quad) ^ cswz) << 3)]; \
} while (0)

#define MM(MH, NH) do { \
  _Pragma("unroll") for (int ks_ = 0; ks_ < 2; ++ks_) \
    _Pragma("unroll") for (int q_ = 0; q_ < 4; ++q_) \
      _Pragma("unroll") for (int p_ = 0; p_ < 2; ++p_) \
        acc[(MH)*4+q_][(NH)*2+p_] = __builtin_amdgcn_mfma_f32_16x16x32_bf16( \
            af[q_][ks_], bf[(NH)*2+p_][ks_], acc[(MH)*4+q_][(NH)*2+p_], 0, 0, 0); \
} while (0)

#define ST_A(KT, HALF) do { if ((KT) < 8) { \
  u16* lb_ = &lds[(((KT)&1)*2 + (HALF))*8192 + (wid << 9)]; \
  const u16* sp_ = Aptr + (size_t)(bm0 + (HALF)*128 + (wid<<3) + srow)*512 + ((KT)<<6) + scg; \
  GLDS(sp_, lb_); GLDS(sp_ + (size_t)64*512, lb_ + 4096); } } while (0)

#define ST_B(KT, HALF) do { if ((KT) < 8) { \
  u16* lb_ = &lds[32768 + (((KT)&1)*2 + (HALF))*8192 + (wid << 9)]; \
  const u16* sp_ = W1t + (size_t)(bn0 + (HALF)*128 + (wid<<3) + srow)*512 + ((KT)<<6) + scg; \
  GLDS(sp_, lb_); GLDS(sp_ + (size_t)64*512, lb_ + 4096); } } while (0)

__global__ __launch_bounds__(512, 2) void gemm1_kernel(
    const void* __restrict__ xraw, const u16* __restrict__ xb,
    const u16* __restrict__ W1t,    // [4096, 512]
    const float* __restrict__ bias, // [4096]
    u16* __restrict__ h_mu, u16* __restrict__ h_lv) {
  __shared__ alignas(16) u16 lds[65536];     // 128 KB
  __shared__ int sflag;
  const int tid = threadIdx.x;

  const u16* Aptr = probe_f32(xraw, 1024, &sflag) ? xb : (const u16*)xraw;

  const int wid = tid >> 6, lane = tid & 63;
  const int wm = wid >> 2, wn = wid & 3;
  const int quad = lane >> 4, c16 = lane & 15, cswz = c16 & 7;
  const int srow = lane >> 3;
  const int scg  = ((lane & 7) ^ srow) << 3;

  // XCD-aware decode, M-fastest within each XCD (x-slab 1 MB stays L2-hot).
  const int id = blockIdx.x;
  const int xcd = id & 7, slot = id >> 3;    // 512 blocks, 64 slots/XCD
  const int bm0 = (xcd * 4 + (slot & 3)) * 256;
  const int bn0 = (slot >> 2) * 256;

  f32x4 acc[8][4] = {};
  bf16x8 af[4][2], bf[4][2];

  // Prologue: kt0 all 4 halves, kt1 B halves (slot order = steady state).
  ST_B(0, 0); ST_B(0, 1); ST_A(0, 0); ST_A(0, 1);
  ST_B(1, 0); ST_B(1, 1);
  VMCNT4;                                    // kt0's 8 loads landed
  __builtin_amdgcn_s_barrier();
  __builtin_amdgcn_sched_barrier(0);

#pragma unroll
  for (int i = 0; i < 4; ++i) {
    const int ka = 2 * i, kb = ka + 1;
    const bool last = (i == 3);
    // ---- K-tile ka (buf 0): phases 1-4
    RD_A(0, 0); RD_B(0, 0); ST_A(kb, 0);
    SYNC_PRE; MM(0, 0); SYNC_POST;
    RD_B(1, 0); ST_A(kb, 1);
    SYNC_PRE; MM(0, 1); SYNC_POST;
    RD_A(1, 0); ST_B(ka + 2, 0);
    SYNC_PRE; MM(1, 0); SYNC_POST;
    ST_B(ka + 2, 1);
    SYNC_PRE; MM(1, 1);
    if (!last) { VMCNT4; } else { VMCNT0; }  // kb fully landed
    SYNC_POST;
    // ---- K-tile kb (buf 1): phases 5-8
    RD_A(0, 1); RD_B(0, 1); ST_A(ka + 2, 0);
    SYNC_PRE; MM(0, 0); SYNC_POST;
    RD_B(1, 1); ST_A(ka + 2, 1);
    SYNC_PRE; MM(0, 1); SYNC_POST;
    RD_A(1, 1); ST_B(kb + 2, 0);
    SYNC_PRE; MM(1, 0); SYNC_POST;
    ST_B(kb + 2, 1);
    SYNC_PRE; MM(1, 1);
    if (!last) { VMCNT4; }                   // kt ka+2 fully landed
    SYNC_POST;                               // this barrier also quiesces LDS
  }

  // Epilogue: per-wave private 16 KB LDS region (all K-loop reads complete
  // after the final phase barrier; regions disjoint per wid -> no barrier).
  // chunk-XOR swizzle: logical (row,col) at row*64 + ((col>>3)^(row&7))*8+(col&7)
  u16* myl = &lds[wid * 8192];
  const bool is_lv = bn0 >= HD;
  u16* dst = is_lv ? h_lv : h_mu;
  const int wncol = wn << 6;
  const int gc0 = (bn0 - (is_lv ? HD : 0)) + wncol;
  const int grow0 = bm0 + (wm << 7);
#pragma unroll
  for (int ni = 0; ni < 4; ++ni) {
    const float bv = bias[bn0 + wncol + ni * 16 + c16];
#pragma unroll
    for (int mi = 0; mi < 8; ++mi)
#pragma unroll
      for (int r = 0; r < 4; ++r) {
        const int row = mi * 16 + (quad << 2) + r;
        const int col = ni * 16 + c16;
        myl[row * 64 + ((((col >> 3) ^ (row & 7)) << 3) | (col & 7))] =
            f2b(fmaxf(acc[mi][ni][r] + bv, 0.f));
      }
  }
#pragma unroll
  for (int it = 0; it < 16; ++it) {
    const int row = (it << 3) + (lane >> 3);
    const int ch = lane & 7;
    const uint4 v = *(const uint4*)&myl[row * 64 + ((ch ^ (row & 7)) << 3)];
    *(uint4*)&dst[(size_t)(grow0 + row) * HD + gc0 + (ch << 3)] = v;
  }
}

#undef RD_A
#undef RD_B
#undef MM
#undef ST_A
#undef ST_B

// ---------------- dual-head GEMM2 + fused loss + last-block finalize --------
// (unchanged, verified structure)
__global__ __launch_bounds__(256) void gemm2_dual(
    const u16* __restrict__ hm, const u16* __restrict__ hl,
    const u16* __restrict__ W2m, const u16* __restrict__ W2l,  // [YD, HD]
    const float* __restrict__ b2m, const float* __restrict__ b2l,
    const void* __restrict__ y,
    const float* __restrict__ Sy, const float* __restrict__ Sy2,
    double* __restrict__ gacc, unsigned* __restrict__ counter,
    float* __restrict__ out) {
  constexpr int K = HD;
  __shared__ alignas(16) u16 Am[64 * 64];    // 8 KB
  __shared__ alignas(16) u16 Al[64 * 64];    // 8 KB
  __shared__ alignas(16) u16 Bm[128 * 64];   // 16 KB
  __shared__ alignas(16) u16 Bl[128 * 64];   // 16 KB
  __shared__ double bs[4];
  __shared__ int sflag;

  const int yf = probe_f32(y, 1024, &sflag);

  const int tid = threadIdx.x, wid = tid >> 6, lane = tid & 63;
  const int MT = NS / 64, NT = YD / 128;     // 128, 4
  const int id = blockIdx.x;
  const int xcd = id & 7, slot = id >> 3;
  const int bm0 = (xcd * (MT >> 3) + slot / NT) * 64;
  const int bn0 = (slot % NT) * 128;

  const int mrow = (wid >> 1) * 32, ncol = (wid & 1) * 64;
  const int quad = lane >> 4, c16 = lane & 15, cswz = c16 & 7;
  const int srow = lane >> 3, sc = lane & 7;
  const int scg  = (sc ^ srow) * 8;

  f32x4 am[2][4] = {}, al[2][4] = {};

  for (int k0 = 0; k0 < K; k0 += 64) {
#pragma unroll
    for (int j = 0; j < 2; ++j) {            // h tiles: 64 rows
      const int grp = wid * 2 + j, row = grp * 8 + srow;
      const size_t go = (size_t)(bm0 + row) * K + (k0 + scg);
      GLDS(hm + go, Am + grp * 512);
      GLDS(hl + go, Al + grp * 512);
    }
#pragma unroll
    for (int j = 0; j < 4; ++j) {            // W2 tiles: 128 rows
      const int grp = wid * 4 + j, row = grp * 8 + srow;
      const size_t go = (size_t)(bn0 + row) * K + (k0 + scg);
      GLDS(W2m + go, Bm + grp * 512);
      GLDS(W2l + go, Bl + grp * 512);
    }
    __syncthreads();
#pragma unroll
    for (int h = 0; h < 2; ++h) {
      const int off = ((h * 4 + quad) ^ cswz) * 8;
      bf16x8 afm[2], afl[2], bfm[4], bfl[4];
#pragma unroll
      for (int mi = 0; mi < 2; ++mi) {
        const int rl = (mrow + mi * 16 + c16) * 64 + off;
        afm[mi] = *(const bf16x8*)&Am[rl];
        afl[mi] = *(const bf16x8*)&Al[rl];
      }
#pragma unroll
      for (int ni = 0; ni < 4; ++ni) {
        const int rl = (ncol + ni * 16 + c16) * 64 + off;
        bfm[ni] = *(const bf16x8*)&Bm[rl];
        bfl[ni] = *(const bf16x8*)&Bl[rl];
      }
#pragma unroll
      for (int mi = 0; mi < 2; ++mi)
#pragma unroll
        for (int ni = 0; ni < 4; ++ni) {
          am[mi][ni] = __builtin_amdgcn_mfma_f32_16x16x32_bf16(
              afm[mi], bfm[ni], am[mi][ni], 0, 0, 0);
          al[mi][ni] = __builtin_amdgcn_mfma_f32_16x16x32_bf16(
              afl[mi], bfl[ni], al[mi][ni], 0, 0, 0);
        }
    }
    __syncthreads();
  }

  const float invN = 1.0f / (float)NS;
  float s = 0.f;
#pragma unroll
  for (int ni = 0; ni < 4; ++ni) {
    const int gcol = bn0 + ncol + ni * 16 + c16;
    const float bmv = b2m[gcol], blv = b2l[gcol];
    const float syv = Sy[gcol], sy2v = Sy2[gcol];
#pragma unroll
    for (int mi = 0; mi < 2; ++mi)
#pragma unroll
      for (int r = 0; r < 4; ++r) {
        const int grow = bm0 + mrow + mi * 16 + quad * 4 + r;
        const float m   = am[mi][ni][r] + bmv;
        const float lvp = al[mi][ni][r] + blv;
        const float w   = 0.5f * expf(-tanhf(lvp));
        const float yv  = ld_in(y, yf, (size_t)grow * YD + gcol);
        s += w * (yv * yv - 2.f * m * yv + (2.f * m * syv - sy2v) * invN);
      }
  }
  for (int off = 32; off > 0; off >>= 1) s += __shfl_down(s, off);
  if (lane == 0) bs[wid] = (double)s;
  __syncthreads();
  if (tid == 0) {
    atomicAdd(gacc, bs[0] + bs[1] + bs[2] + bs[3]);
    __threadfence();
    const unsigned old = atomicAdd(counter, 1u);
    if (old == gridDim.x - 1) {
      const double g = atomicAdd(gacc, 0.0);
      out[0] = (float)(-g / (double)NS);
    }
  }
}

// ---------------- launch ----------------
extern "C" void kernel_launch(void* const* d_in, const int* in_sizes, int n_in,
                              void* d_out, int out_size, void* d_ws, size_t ws_size,
                              hipStream_t stream) {
  char* ws = (char*)d_ws;
  double*   gacc    = (double*)ws;               // [0,8)
  unsigned* counter = (unsigned*)(ws + 8);       // [8,12)
  float*    Sy      = (float*)(ws + 128);        // 512 f32
  float*    Sy2     = (float*)(ws + 2176);       // 512 f32
  float*    biasv   = (float*)(ws + 4224);       // 5120 f32 -> ends 24704
  u16* xb   = (u16*)(ws + 24704);                // [NS,XD] bf16, 8 MB
  u16* W1t  = xb + (size_t)NS * XD;              // [4096,512] 4 MB (both heads)
  u16* W2tm = W1t + (size_t)2 * HD * XD;         // [YD,HD] 2 MB
  u16* W2tl = W2tm + (size_t)YD * HD;            // 2 MB
  u16* h_mu = W2tl + (size_t)YD * HD;            // [NS,HD] bf16, 32 MB
  u16* h_lv = h_mu + (size_t)NS * HD;            // 32 MB  (~80 MB total)

  hipMemsetAsync(d_ws, 0, 4224, stream);         // gacc + counter + Sy + Sy2

  prep_all<<<2049 + 1024 + 64, 256, 0, stream>>>(
      d_in[0], d_in[2], d_in[3], d_in[4], d_in[5],
      d_in[6], d_in[7], d_in[8], d_in[9], d_in[1],
      xb, biasv, W1t, W2tm, W2tl, Sy, Sy2);

  const float* b1  = biasv;               // [4096] = b1m|b1l
  const float* b2m = biasv + 4096, *b2l = biasv + 4608;

  gemm1_kernel<<<(NS / 256) * ((2 * HD) / 256), 512, 0, stream>>>(
      d_in[0], xb, W1t, b1, h_mu, h_lv);

  gemm2_dual<<<(NS / 64) * (YD / 128), 256, 0, stream>>>(
      h_mu, h_lv, W2tm, W2tl, b2m, b2l, d_in[1], Sy, Sy2,
      gacc, counter, (float*)d_out);
}

// Round 2
// 214.092 us; speedup vs baseline: 1.0835x; 1.0520x over previous
//
#include <hip/hip_runtime.h>
#include <hip/hip_bf16.h>
#include <stdint.h>

// Problem constants (fixed by the reference)
#define NS   8192
#define XD   512
#define HD   2048
#define YD   512

typedef unsigned short u16;
using bf16x8 = __attribute__((ext_vector_type(8))) short;
using f32x4  = __attribute__((ext_vector_type(4))) float;

__device__ __forceinline__ float bf2f(u16 u) {
  union { uint32_t i; float f; } v; v.i = ((uint32_t)u) << 16; return v.f;
}
__device__ __forceinline__ u16 f2b(float f) {
  __hip_bfloat16 hb = __float2bfloat16(f);
  return *(const u16*)&hb;
}
// dtype-adaptive element load: f32 flag ? read float : read bf16
__device__ __forceinline__ float ld_in(const void* p, int f32, size_t i) {
  return f32 ? ((const float*)p)[i] : bf2f(((const u16*)p)[i]);
}
#define GLDS(gp, lp) __builtin_amdgcn_global_load_lds( \
    (__attribute__((address_space(1))) void*)(gp),     \
    (__attribute__((address_space(3))) void*)(lp), 16, 0, 0)

// ---------------- per-block dtype self-detection ----------------------------
__device__ __forceinline__ int probe_f32(const void* p, int n_u16, int* sflag) {
  if (threadIdx.x == 0) *sflag = 0;
  __syncthreads();
  const u16* q = (const u16*)p;
  int wild = 0;
  for (int i = threadIdx.x; i < n_u16; i += blockDim.x) {
    float v = bf2f(q[i]);
    if (!(fabsf(v) <= 1000.0f)) wild = 1;   // catches huge AND NaN
  }
  if (wild) *sflag = 1;
  __syncthreads();
  int r = *sflag;
  __syncthreads();                          // safe for back-to-back reuse
  return r;
}

// ---------------- fused prep: x->bf16, biases, 4 transposes, ystats ---------
// grid: [0,2048) x-convert | 2048 biases | [2049,3073) transposes |
//       [3073,3137) y column stats
__global__ __launch_bounds__(256) void prep_all(
    const void* __restrict__ x,
    const void* w1m, const void* b1m, const void* w2m, const void* b2m,
    const void* w1l, const void* b1l, const void* w2l, const void* b2l,
    const void* __restrict__ y,
    u16* __restrict__ xb, float* __restrict__ biasv,
    u16* __restrict__ W1t, u16* __restrict__ W2tm, u16* __restrict__ W2tl,
    float* __restrict__ Sy, float* __restrict__ Sy2) {
  __shared__ u16 tile[64 * 72];              // transpose staging (9216 B)
  __shared__ int sflag;
  const int b = blockIdx.x;
  const int tid = threadIdx.x;

  if (b < 2048) {                            // ---- x conversion (f32 only)
    if (!probe_f32(x, 1024, &sflag)) return; // bf16 -> gemm1 reads x directly
    const size_t base = (size_t)b * 2048 + (size_t)tid * 8;
    alignas(16) u16 o[8];
    const float4* s = (const float4*)((const float*)x + base);
    float4 v0 = s[0], v1 = s[1];
    o[0]=f2b(v0.x); o[1]=f2b(v0.y); o[2]=f2b(v0.z); o[3]=f2b(v0.w);
    o[4]=f2b(v1.x); o[5]=f2b(v1.y); o[6]=f2b(v1.z); o[7]=f2b(v1.w);
    *(uint4*)(xb + base) = *(const uint4*)o;
  } else if (b == 2048) {                    // ---- biases -> f32
    const int f3 = probe_f32(b1m, 1024, &sflag);
    const int f5 = probe_f32(b2m, 512, &sflag);
    const int f7 = probe_f32(b1l, 1024, &sflag);
    const int f9 = probe_f32(b2l, 512, &sflag);
    for (int i = tid; i < 5120; i += 256) {
      float v;
      if (i < 2048)      v = ld_in(b1m, f3, i);
      else if (i < 4096) v = ld_in(b1l, f7, i - 2048);
      else if (i < 4608) v = ld_in(b2m, f5, i - 4096);
      else               v = ld_in(b2l, f9, i - 4608);
      biasv[i] = v;
    }
  } else if (b < 3073) {                     // ---- 64x64-tile transposes
    const int id = b - 2049, which = id >> 8, t = id & 255;
    const void* in; u16* out; int R, C;
    if (which == 0)      { in = w1m; out = W1t;                   R = XD; C = HD; }
    else if (which == 1) { in = w2m; out = W2tm;                  R = HD; C = YD; }
    else if (which == 2) { in = w1l; out = W1t + (size_t)HD * XD; R = XD; C = HD; }
    else                 { in = w2l; out = W2tl;                  R = HD; C = YD; }
    const int f = probe_f32(in, 1024, &sflag);
    const int nbx = C >> 6;
    const int c0 = (t % nbx) * 64, r0 = (t / nbx) * 64;
    const int r = tid >> 2, cc = (tid & 3) * 16;
    if (f) {
      const float4* s = (const float4*)((const float*)in + (size_t)(r0 + r) * C + c0 + cc);
#pragma unroll
      for (int k = 0; k < 4; ++k) {
        float4 v = s[k];
        tile[r * 72 + cc + k * 4 + 0] = f2b(v.x);
        tile[r * 72 + cc + k * 4 + 1] = f2b(v.y);
        tile[r * 72 + cc + k * 4 + 2] = f2b(v.z);
        tile[r * 72 + cc + k * 4 + 3] = f2b(v.w);
      }
    } else {
      const uint4* s = (const uint4*)((const u16*)in + (size_t)(r0 + r) * C + c0 + cc);
      *(uint4*)&tile[r * 72 + cc]     = s[0];
      *(uint4*)&tile[r * 72 + cc + 8] = s[1];
    }
    __syncthreads();
    const int i = tid >> 2, jc = (tid & 3) * 16;
    alignas(16) u16 o[16];
#pragma unroll
    for (int j = 0; j < 16; ++j) o[j] = tile[(jc + j) * 72 + i];
    uint4* dq = (uint4*)&out[(size_t)(c0 + i) * R + r0 + jc];
    dq[0] = ((const uint4*)o)[0];
    dq[1] = ((const uint4*)o)[1];
  } else {                                   // ---- y column stats (64 blocks)
    const int id2 = b - 3073;
    const int yf = probe_f32(y, 1024, &sflag);
    const int half = tid >> 7;               // 0/1
    const int c0 = (tid & 127) * 4;
    const int r0 = id2 * 128 + half * 64;
    float s0 = 0.f, s1 = 0.f, s2 = 0.f, s3 = 0.f;
    float q0 = 0.f, q1 = 0.f, q2 = 0.f, q3 = 0.f;
    for (int r = r0; r < r0 + 64; r += 4) {
#pragma unroll
      for (int rr = 0; rr < 4; ++rr) {
        float v0, v1, v2, v3;
        if (yf) {
          const float4 t4 = *(const float4*)((const float*)y + (size_t)(r + rr) * YD + c0);
          v0 = t4.x; v1 = t4.y; v2 = t4.z; v3 = t4.w;
        } else {
          const uint2 t2 = *(const uint2*)((const u16*)y + (size_t)(r + rr) * YD + c0);
          v0 = bf2f((u16)(t2.x & 0xffff)); v1 = bf2f((u16)(t2.x >> 16));
          v2 = bf2f((u16)(t2.y & 0xffff)); v3 = bf2f((u16)(t2.y >> 16));
        }
        s0 += v0; q0 += v0 * v0;  s1 += v1; q1 += v1 * v1;
        s2 += v2; q2 += v2 * v2;  s3 += v3; q3 += v3 * v3;
      }
    }
    atomicAdd(&Sy[c0],     s0);  atomicAdd(&Sy2[c0],     q0);
    atomicAdd(&Sy[c0 + 1], s1);  atomicAdd(&Sy2[c0 + 1], q1);
    atomicAdd(&Sy[c0 + 2], s2);  atomicAdd(&Sy2[c0 + 2], q2);
    atomicAdd(&Sy[c0 + 3], s3);  atomicAdd(&Sy2[c0 + 3], q3);
  }
}

// ---------------- shared sync/pipeline macros -------------------------------
#define SYNC_PRE do { \
  __builtin_amdgcn_sched_barrier(0); \
  __builtin_amdgcn_s_barrier(); \
  asm volatile("s_waitcnt lgkmcnt(0)" ::: "memory"); \
  __builtin_amdgcn_sched_barrier(0); \
  __builtin_amdgcn_s_setprio(1); } while (0)
#define SYNC_POST do { \
  __builtin_amdgcn_s_setprio(0); \
  __builtin_amdgcn_sched_barrier(0); \
  __builtin_amdgcn_s_barrier(); \
  __builtin_amdgcn_sched_barrier(0); } while (0)
#define VMCNT(N) asm volatile("s_waitcnt vmcnt(" #N ")" ::: "memory")

// ---------------- GEMM1: 256x256 tile, 8-phase counted-vmcnt pipeline -------
// (verified round-0; unchanged)
#define RD_A(MH, BUF) do { \
  const u16* ab_ = &lds[((BUF)*2 + wm) * 8192]; \
  _Pragma("unroll") for (int q_ = 0; q_ < 4; ++q_) \
    _Pragma("unroll") for (int ks_ = 0; ks_ < 2; ++ks_) \
      af[q_][ks_] = *(const bf16x8*)&ab_[((MH)*64 + q_*16 + c16)*64 + (((ks_*4+quad) ^ cswz) << 3)]; \
} while (0)

#define RD_B(NH, BUF) do { \
  const u16* bb_ = &lds[32768 + ((BUF)*2 + (wn>>1)) * 8192]; \
  _Pragma("unroll") for (int p_ = 0; p_ < 2; ++p_) \
    _Pragma("unroll") for (int ks_ = 0; ks_ < 2; ++ks_) \
      bf[(NH)*2+p_][ks_] = *(const bf16x8*)&bb_[((wn&1)*64 + ((NH)*2+p_)*16 + c16)*64 + (((ks_*4+quad) ^ cswz) << 3)]; \
} while (0)

#define MM(MH, NH) do { \
  _Pragma("unroll") for (int ks_ = 0; ks_ < 2; ++ks_) \
    _Pragma("unroll") for (int q_ = 0; q_ < 4; ++q_) \
      _Pragma("unroll") for (int p_ = 0; p_ < 2; ++p_) \
        acc[(MH)*4+q_][(NH)*2+p_] = __builtin_amdgcn_mfma_f32_16x16x32_bf16( \
            af[q_][ks_], bf[(NH)*2+p_][ks_], acc[(MH)*4+q_][(NH)*2+p_], 0, 0, 0); \
} while (0)

#define ST_A(KT, HALF) do { if ((KT) < 8) { \
  u16* lb_ = &lds[(((KT)&1)*2 + (HALF))*8192 + (wid << 9)]; \
  const u16* sp_ = Aptr + (size_t)(bm0 + (HALF)*128 + (wid<<3) + srow)*512 + ((KT)<<6) + scg; \
  GLDS(sp_, lb_); GLDS(sp_ + (size_t)64*512, lb_ + 4096); } } while (0)

#define ST_B(KT, HALF) do { if ((KT) < 8) { \
  u16* lb_ = &lds[32768 + (((KT)&1)*2 + (HALF))*8192 + (wid << 9)]; \
  const u16* sp_ = W1t + (size_t)(bn0 + (HALF)*128 + (wid<<3) + srow)*512 + ((KT)<<6) + scg; \
  GLDS(sp_, lb_); GLDS(sp_ + (size_t)64*512, lb_ + 4096); } } while (0)

__global__ __launch_bounds__(512, 2) void gemm1_kernel(
    const void* __restrict__ xraw, const u16* __restrict__ xb,
    const u16* __restrict__ W1t,    // [4096, 512]
    const float* __restrict__ bias, // [4096]
    u16* __restrict__ h_mu, u16* __restrict__ h_lv) {
  __shared__ alignas(16) u16 lds[65536];     // 128 KB
  __shared__ int sflag;
  const int tid = threadIdx.x;

  const u16* Aptr = probe_f32(xraw, 1024, &sflag) ? xb : (const u16*)xraw;

  const int wid = tid >> 6, lane = tid & 63;
  const int wm = wid >> 2, wn = wid & 3;
  const int quad = lane >> 4, c16 = lane & 15, cswz = c16 & 7;
  const int srow = lane >> 3;
  const int scg  = ((lane & 7) ^ srow) << 3;

  const int id = blockIdx.x;
  const int xcd = id & 7, slot = id >> 3;    // 512 blocks, 64 slots/XCD
  const int bm0 = (xcd * 4 + (slot & 3)) * 256;
  const int bn0 = (slot >> 2) * 256;

  f32x4 acc[8][4] = {};
  bf16x8 af[4][2], bf[4][2];

  ST_B(0, 0); ST_B(0, 1); ST_A(0, 0); ST_A(0, 1);
  ST_B(1, 0); ST_B(1, 1);
  VMCNT(4);
  __builtin_amdgcn_s_barrier();
  __builtin_amdgcn_sched_barrier(0);

#pragma unroll
  for (int i = 0; i < 4; ++i) {
    const int ka = 2 * i, kb = ka + 1;
    const bool last = (i == 3);
    RD_A(0, 0); RD_B(0, 0); ST_A(kb, 0);
    SYNC_PRE; MM(0, 0); SYNC_POST;
    RD_B(1, 0); ST_A(kb, 1);
    SYNC_PRE; MM(0, 1); SYNC_POST;
    RD_A(1, 0); ST_B(ka + 2, 0);
    SYNC_PRE; MM(1, 0); SYNC_POST;
    ST_B(ka + 2, 1);
    SYNC_PRE; MM(1, 1);
    if (!last) { VMCNT(4); } else { VMCNT(0); }
    SYNC_POST;
    RD_A(0, 1); RD_B(0, 1); ST_A(ka + 2, 0);
    SYNC_PRE; MM(0, 0); SYNC_POST;
    RD_B(1, 1); ST_A(ka + 2, 1);
    SYNC_PRE; MM(0, 1); SYNC_POST;
    RD_A(1, 1); ST_B(kb + 2, 0);
    SYNC_PRE; MM(1, 0); SYNC_POST;
    ST_B(kb + 2, 1);
    SYNC_PRE; MM(1, 1);
    if (!last) { VMCNT(4); }
    SYNC_POST;
  }

  u16* myl = &lds[wid * 8192];
  const bool is_lv = bn0 >= HD;
  u16* dst = is_lv ? h_lv : h_mu;
  const int wncol = wn << 6;
  const int gc0 = (bn0 - (is_lv ? HD : 0)) + wncol;
  const int grow0 = bm0 + (wm << 7);
#pragma unroll
  for (int ni = 0; ni < 4; ++ni) {
    const float bv = bias[bn0 + wncol + ni * 16 + c16];
#pragma unroll
    for (int mi = 0; mi < 8; ++mi)
#pragma unroll
      for (int r = 0; r < 4; ++r) {
        const int row = mi * 16 + (quad << 2) + r;
        const int col = ni * 16 + c16;
        myl[row * 64 + ((((col >> 3) ^ (row & 7)) << 3) | (col & 7))] =
            f2b(fmaxf(acc[mi][ni][r] + bv, 0.f));
      }
  }
#pragma unroll
  for (int it = 0; it < 16; ++it) {
    const int row = (it << 3) + (lane >> 3);
    const int ch = lane & 7;
    const uint4 v = *(const uint4*)&myl[row * 64 + ((ch ^ (row & 7)) << 3)];
    *(uint4*)&dst[(size_t)(grow0 + row) * HD + gc0 + (ch << 3)] = v;
  }
}

#undef RD_A
#undef RD_B
#undef MM
#undef ST_A
#undef ST_B

// ---------------- GEMM2: dual-head 128x128, 8-phase counted-vmcnt -----------
// mu = hm @ W2m^T, lvp = hl @ W2l^T (both [8192,512]), fused loss epilogue.
// 512 thr = 8 waves (4M x 2N); per wave per head 32x64 out; acc 64 f32/thr.
// LDS 128 KB: buf b @ b*32768 u16: Am@0 Al@8192 Bm@16384 Bl@24576
// (each region [128 rows][64 cols] u16 = 16 KB; XOR-swizzled source cols).
// Phase p reads (buf of current tile): ph1 Am+Bm(n0) | ph2 Bm(n1) |
// ph3 Al+Bl(n0) | ph4 Bl(n1); ph5-8 same on other buf. Last read of region
// R is thus ph{1,2,3,4}; one ST per phase into the region freed by the
// previous phase (safe: a full s_barrier separates):
//  ph1: Bl(2i+1)  ph2: Am(2i+2)  ph3: Bm(2i+2)  ph4: Al(2i+2)
//  ph5: Bl(2i+2)  ph6: Am(2i+3)  ph7: Bm(2i+3)  ph8: Al(2i+3)
// Each ST = 2 GLDS. Steady state: vmcnt(10) at END of even phases (5 STs
// allowed in flight; everything older -> landed, exactly covering the two
// regions read at the start of the next odd phase). Peeled last iteration
// drains 8 -> 4 -> 0. K=2048 -> 32 K-tiles, 15 rolled iters + 1 peeled.
#define RD_AF(dstf, RBASE, BUF) do { \
  _Pragma("unroll") for (int mi_ = 0; mi_ < 2; ++mi_) \
    _Pragma("unroll") for (int ks_ = 0; ks_ < 2; ++ks_) \
      dstf[mi_][ks_] = *(const bf16x8*)&lds[(BUF)*32768 + (RBASE) + \
          (wm*32 + mi_*16 + c16)*64 + (((ks_*4+quad) ^ cswz) << 3)]; \
} while (0)

#define RD_BF(RBASE, BUF, NH) do { \
  _Pragma("unroll") for (int p_ = 0; p_ < 2; ++p_) \
    _Pragma("unroll") for (int ks_ = 0; ks_ < 2; ++ks_) \
      bfr[p_][ks_] = *(const bf16x8*)&lds[(BUF)*32768 + (RBASE) + \
          (wn*64 + ((NH)*2+p_)*16 + c16)*64 + (((ks_*4+quad) ^ cswz) << 3)]; \
} while (0)

#define MM2(accv, aff, NH) do { \
  _Pragma("unroll") for (int ks_ = 0; ks_ < 2; ++ks_) \
    _Pragma("unroll") for (int mi_ = 0; mi_ < 2; ++mi_) \
      _Pragma("unroll") for (int p_ = 0; p_ < 2; ++p_) \
        accv[mi_][(NH)*2+p_] = __builtin_amdgcn_mfma_f32_16x16x32_bf16( \
            aff[mi_][ks_], bfr[p_][ks_], accv[mi_][(NH)*2+p_], 0, 0, 0); \
} while (0)

#define ST_R(KT, SRC, RBASE) do { \
  u16* lb_ = &lds[(((KT)&1)*32768) + (RBASE) + (wid << 9)]; \
  const u16* sp_ = (SRC) + (size_t)(KT)*64; \
  GLDS(sp_, lb_); GLDS(sp_ + (size_t)64*2048, lb_ + 4096); \
} while (0)

#define RAm 0
#define RAl 8192
#define RBm 16384
#define RBl 24576

__global__ __launch_bounds__(512, 2) void gemm2_dual(
    const u16* __restrict__ hm, const u16* __restrict__ hl,
    const u16* __restrict__ W2m, const u16* __restrict__ W2l,  // [YD, HD]
    const float* __restrict__ b2m, const float* __restrict__ b2l,
    const void* __restrict__ y,
    const float* __restrict__ Sy, const float* __restrict__ Sy2,
    double* __restrict__ gacc, unsigned* __restrict__ counter,
    float* __restrict__ out) {
  __shared__ alignas(16) u16 lds[65536];     // 128 KB
  __shared__ double bs[8];
  __shared__ int sflag;

  const int yf = probe_f32(y, 1024, &sflag);

  const int tid = threadIdx.x, wid = tid >> 6, lane = tid & 63;
  const int wm = wid >> 1, wn = wid & 1;     // 4M x 2N waves
  const int quad = lane >> 4, c16 = lane & 15, cswz = c16 & 7;
  const int srow = lane >> 3;
  const int scg  = ((lane & 7) ^ srow) << 3;

  // 256 blocks = 64 m-tiles x 4 n-tiles; N-fastest within XCD so the 4 MB
  // W2 pair stays L2-resident while the h slab streams (h is L3-hot anyway).
  const int id = blockIdx.x;
  const int xcd = id & 7, slot = id >> 3;    // 32 slots/XCD
  const int bm0 = (xcd * 8 + (slot >> 2)) * 128;
  const int bn0 = (slot & 3) * 128;

  // Per-thread staging source bases (row = wid*8 + srow of the 128-row tile).
  const u16* aM = hm  + (size_t)(bm0 + (wid << 3) + srow) * HD + scg;
  const u16* aL = hl  + (size_t)(bm0 + (wid << 3) + srow) * HD + scg;
  const u16* bM = W2m + (size_t)(bn0 + (wid << 3) + srow) * HD + scg;
  const u16* bL = W2l + (size_t)(bn0 + (wid << 3) + srow) * HD + scg;

  f32x4 am[2][4] = {}, al[2][4] = {};
  bf16x8 afm[2][2], afl[2][2], bfr[2][2];

  // Prologue: tile0 all 4 regions, tile1 Am/Bm/Al (Bl(1) comes at ph1).
  ST_R(0, aM, RAm); ST_R(0, bM, RBm); ST_R(0, aL, RAl); ST_R(0, bL, RBl);
  ST_R(1, aM, RAm); ST_R(1, bM, RBm); ST_R(1, aL, RAl);
  VMCNT(10);                                 // tile0 Am+Bm landed
  __builtin_amdgcn_s_barrier();
  __builtin_amdgcn_sched_barrier(0);

#pragma unroll 1
  for (int i = 0; i < 15; ++i) {
    const int ka = 2 * i, kb = ka + 1;
    // ---- tile ka (buf 0)
    RD_AF(afm, RAm, 0); RD_BF(RBm, 0, 0); ST_R(kb,     bL, RBl);
    SYNC_PRE; MM2(am, afm, 0); SYNC_POST;
    RD_BF(RBm, 0, 1);                       ST_R(ka + 2, aM, RAm);
    SYNC_PRE; MM2(am, afm, 1); VMCNT(10); SYNC_POST;
    RD_AF(afl, RAl, 0); RD_BF(RBl, 0, 0); ST_R(ka + 2, bM, RBm);
    SYNC_PRE; MM2(al, afl, 0); SYNC_POST;
    RD_BF(RBl, 0, 1);                       ST_R(ka + 2, aL, RAl);
    SYNC_PRE; MM2(al, afl, 1); VMCNT(10); SYNC_POST;
    // ---- tile kb (buf 1)
    RD_AF(afm, RAm, 1); RD_BF(RBm, 1, 0); ST_R(ka + 2, bL, RBl);
    SYNC_PRE; MM2(am, afm, 0); SYNC_POST;
    RD_BF(RBm, 1, 1);                       ST_R(kb + 2, aM, RAm);
    SYNC_PRE; MM2(am, afm, 1); VMCNT(10); SYNC_POST;
    RD_AF(afl, RAl, 1); RD_BF(RBl, 1, 0); ST_R(kb + 2, bM, RBm);
    SYNC_PRE; MM2(al, afl, 0); SYNC_POST;
    RD_BF(RBl, 1, 1);                       ST_R(kb + 2, aL, RAl);
    SYNC_PRE; MM2(al, afl, 1); VMCNT(10); SYNC_POST;
  }
  // ---- peeled last iteration: tiles 30 (buf 0), 31 (buf 1); drain vmcnt.
  {
    RD_AF(afm, RAm, 0); RD_BF(RBm, 0, 0); ST_R(31, bL, RBl);
    SYNC_PRE; MM2(am, afm, 0); SYNC_POST;
    RD_BF(RBm, 0, 1);
    SYNC_PRE; MM2(am, afm, 1); VMCNT(8); SYNC_POST;
    RD_AF(afl, RAl, 0); RD_BF(RBl, 0, 0);
    SYNC_PRE; MM2(al, afl, 0); SYNC_POST;
    RD_BF(RBl, 0, 1);
    SYNC_PRE; MM2(al, afl, 1); VMCNT(4); SYNC_POST;
    RD_AF(afm, RAm, 1); RD_BF(RBm, 1, 0);
    SYNC_PRE; MM2(am, afm, 0); SYNC_POST;
    RD_BF(RBm, 1, 1);
    SYNC_PRE; MM2(am, afm, 1); VMCNT(0); SYNC_POST;
    RD_AF(afl, RAl, 1); RD_BF(RBl, 1, 0);
    SYNC_PRE; MM2(al, afl, 0); SYNC_POST;
    RD_BF(RBl, 1, 1);
    SYNC_PRE; MM2(al, afl, 1); SYNC_POST;
  }

  // Fused loss epilogue: mu & lvp in registers.
  // term: w * [ y^2 - 2*mu*y + (2*mu*Sy_d - Sy2_d)/N ], w = 0.5*e^{-tanh(lvp)}
  const float invN = 1.0f / (float)NS;
  float s = 0.f;
#pragma unroll
  for (int ni = 0; ni < 4; ++ni) {
    const int gcol = bn0 + wn * 64 + ni * 16 + c16;
    const float bmv = b2m[gcol], blv = b2l[gcol];
    const float syv = Sy[gcol], sy2v = Sy2[gcol];
#pragma unroll
    for (int mi = 0; mi < 2; ++mi)
#pragma unroll
      for (int r = 0; r < 4; ++r) {
        const int grow = bm0 + wm * 32 + mi * 16 + quad * 4 + r;
        const float m   = am[mi][ni][r] + bmv;
        const float lvp = al[mi][ni][r] + blv;
        const float w   = 0.5f * expf(-tanhf(lvp));
        const float yv  = ld_in(y, yf, (size_t)grow * YD + gcol);
        s += w * (yv * yv - 2.f * m * yv + (2.f * m * syv - sy2v) * invN);
      }
  }
  for (int off = 32; off > 0; off >>= 1) s += __shfl_down(s, off);
  if (lane == 0) bs[wid] = (double)s;
  __syncthreads();
  if (tid == 0) {
    atomicAdd(gacc, bs[0] + bs[1] + bs[2] + bs[3] +
                    bs[4] + bs[5] + bs[6] + bs[7]);
    __threadfence();
    const unsigned old = atomicAdd(counter, 1u);
    if (old == gridDim.x - 1) {
      const double g = atomicAdd(gacc, 0.0);
      out[0] = (float)(-g / (double)NS);
    }
  }
}

// ---------------- launch ----------------
extern "C" void kernel_launch(void* const* d_in, const int* in_sizes, int n_in,
                              void* d_out, int out_size, void* d_ws, size_t ws_size,
                              hipStream_t stream) {
  char* ws = (char*)d_ws;
  double*   gacc    = (double*)ws;               // [0,8)
  unsigned* counter = (unsigned*)(ws + 8);       // [8,12)
  float*    Sy      = (float*)(ws + 128);        // 512 f32
  float*    Sy2     = (float*)(ws + 2176);       // 512 f32
  float*    biasv   = (float*)(ws + 4224);       // 5120 f32 -> ends 24704
  u16* xb   = (u16*)(ws + 24704);                // [NS,XD] bf16, 8 MB
  u16* W1t  = xb + (size_t)NS * XD;              // [4096,512] 4 MB (both heads)
  u16* W2tm = W1t + (size_t)2 * HD * XD;         // [YD,HD] 2 MB
  u16* W2tl = W2tm + (size_t)YD * HD;            // 2 MB
  u16* h_mu = W2tl + (size_t)YD * HD;            // [NS,HD] bf16, 32 MB
  u16* h_lv = h_mu + (size_t)NS * HD;            // 32 MB  (~80 MB total)

  hipMemsetAsync(d_ws, 0, 4224, stream);         // gacc + counter + Sy + Sy2

  prep_all<<<2049 + 1024 + 64, 256, 0, stream>>>(
      d_in[0], d_in[2], d_in[3], d_in[4], d_in[5],
      d_in[6], d_in[7], d_in[8], d_in[9], d_in[1],
      xb, biasv, W1t, W2tm, W2tl, Sy, Sy2);

  const float* b1  = biasv;               // [4096] = b1m|b1l
  const float* b2m = biasv + 4096, *b2l = biasv + 4608;

  gemm1_kernel<<<(NS / 256) * ((2 * HD) / 256), 512, 0, stream>>>(
      d_in[0], xb, W1t, b1, h_mu, h_lv);

  gemm2_dual<<<(NS / 128) * (YD / 128), 512, 0, stream>>>(
      h_mu, h_lv, W2tm, W2tl, b2m, b2l, d_in[1], Sy, Sy2,
      gacc, counter, (float*)d_out);
}